// Round 2
// baseline (838.178 us; speedup 1.0000x reference)
//
#include <hip/hip_runtime.h>
#include <math.h>

// TopK router: logits = x @ gate_w^T, softmax, top-2, renormalize.
// M=32768 tokens, K=4096, E=64 experts.
// Outputs (concat, harness reads whole buffer as float32):
//   d_out[0 .. 2M)  : top-2 weights (descending)
//   d_out[2M .. 4M) : top-2 expert indices, stored as float values
//
// Strategy: fast fp32 register-tiled GEMM + fused top-2. Tokens whose
// top-1/2 or top-2/3 logit gap < TAU are re-computed in fp64 (exact
// ordering) inside the same block — near-tie flips vs the numpy/jax
// reference were the R1 failure mode (weights passed, indices absmax 47).

#define TPB 64      // tokens per block
#define BK  64      // K-chunk
#define PAD 68      // padded leading dim (68 words, rows stay 16B-aligned)
#define TAU 1e-3f   // near-tie refine threshold (fp32 accum noise ~5e-6)

__global__ __launch_bounds__(256, 2)
void router_gemm_topk(const float* __restrict__ x,
                      const float* __restrict__ gw,
                      float* __restrict__ out,
                      int M, int K) {
    __shared__ float As[BK][PAD];   // [kk][token]  (k-major)
    __shared__ float Bs[BK][PAD];   // [kk][expert] (k-major)
    __shared__ int   flags[TPB];
    __shared__ double Ld[64];

    const int t   = threadIdx.x;
    const int tx  = t & 15;         // expert group: experts 4*tx..4*tx+3
    const int ty  = t >> 4;         // token group:  tokens  4*ty..4*ty+3
    const long tok0 = (long)blockIdx.x * TPB;

    const int lrow = t >> 2;        // staging row 0..63
    const int lc   = t & 3;         // staging quarter

    float acc[4][4];
#pragma unroll
    for (int i = 0; i < 4; ++i)
#pragma unroll
        for (int j = 0; j < 4; ++j) acc[i][j] = 0.0f;

    const float* xrow = x + (tok0 + lrow) * (long)K;
    const float* grow = gw + lrow * (long)K;

    for (int k0 = 0; k0 < K; k0 += BK) {
        float4 av[4], bv[4];
#pragma unroll
        for (int j = 0; j < 4; ++j) {
            const int koff = k0 + 16 * j + 4 * lc;
            av[j] = *reinterpret_cast<const float4*>(xrow + koff);
            bv[j] = *reinterpret_cast<const float4*>(grow + koff);
        }
        __syncthreads();
#pragma unroll
        for (int j = 0; j < 4; ++j) {
            const int kl = 16 * j + 4 * lc;
            As[kl + 0][lrow] = av[j].x;
            As[kl + 1][lrow] = av[j].y;
            As[kl + 2][lrow] = av[j].z;
            As[kl + 3][lrow] = av[j].w;
            Bs[kl + 0][lrow] = bv[j].x;
            Bs[kl + 1][lrow] = bv[j].y;
            Bs[kl + 2][lrow] = bv[j].z;
            Bs[kl + 3][lrow] = bv[j].w;
        }
        __syncthreads();
#pragma unroll 8
        for (int kk = 0; kk < BK; ++kk) {
            const float4 a = *reinterpret_cast<const float4*>(&As[kk][ty << 2]);
            const float4 b = *reinterpret_cast<const float4*>(&Bs[kk][tx << 2]);
            acc[0][0] = fmaf(a.x, b.x, acc[0][0]);
            acc[0][1] = fmaf(a.x, b.y, acc[0][1]);
            acc[0][2] = fmaf(a.x, b.z, acc[0][2]);
            acc[0][3] = fmaf(a.x, b.w, acc[0][3]);
            acc[1][0] = fmaf(a.y, b.x, acc[1][0]);
            acc[1][1] = fmaf(a.y, b.y, acc[1][1]);
            acc[1][2] = fmaf(a.y, b.z, acc[1][2]);
            acc[1][3] = fmaf(a.y, b.w, acc[1][3]);
            acc[2][0] = fmaf(a.z, b.x, acc[2][0]);
            acc[2][1] = fmaf(a.z, b.y, acc[2][1]);
            acc[2][2] = fmaf(a.z, b.z, acc[2][2]);
            acc[2][3] = fmaf(a.z, b.w, acc[2][3]);
            acc[3][0] = fmaf(a.w, b.x, acc[3][0]);
            acc[3][1] = fmaf(a.w, b.y, acc[3][1]);
            acc[3][2] = fmaf(a.w, b.z, acc[3][2]);
            acc[3][3] = fmaf(a.w, b.w, acc[3][3]);
        }
    }

    // ---- dump logits into LDS (reuse As region: [64 tokens][PAD]) ----
    __syncthreads();
    float* Ls = &As[0][0];
#pragma unroll
    for (int i = 0; i < 4; ++i) {
        float4 v = make_float4(acc[i][0], acc[i][1], acc[i][2], acc[i][3]);
        *reinterpret_cast<float4*>(Ls + (long)(4 * ty + i) * PAD + 4 * tx) = v;
    }
    __syncthreads();

    // ---- top-3 scan + provisional output + near-tie flag ----
    if (t < TPB) {
        const float* row = Ls + (long)t * PAD;
        float m1 = -INFINITY, m2 = -INFINITY, m3 = -INFINITY;
        int i1 = 0, i2 = 0;
#pragma unroll 8
        for (int e = 0; e < 64; ++e) {
            const float v = row[e];
            if (v > m1)      { m3 = m2; m2 = m1; i2 = i1; m1 = v; i1 = e; }
            else if (v > m2) { m3 = m2; m2 = v; i2 = e; }
            else if (v > m3) { m3 = v; }
        }
        const float e2 = expf(m2 - m1);
        const float s  = 1.0f + e2;

        const long g = tok0 + t;
        out[2 * g + 0] = 1.0f / s;
        out[2 * g + 1] = e2 / s;
        float* oi = out + 2 * (long)M;
        oi[2 * g + 0] = (float)i1;
        oi[2 * g + 1] = (float)i2;

        flags[t] = ((m1 - m2) < TAU) | ((m2 - m3) < TAU);
    }
    __syncthreads();

    // ---- fp64 refine for near-tie tokens (rare; uniform control flow) ----
    for (int tk = 0; tk < TPB; ++tk) {
        if (flags[tk]) {
            if (t < 64) {
                // thread t = expert t: exact fp64 dot over the token row
                const float* xr = x + (tok0 + tk) * (long)K;
                const float* gr = gw + (long)t * (long)K;
                double s0 = 0.0, s1 = 0.0, s2 = 0.0, s3 = 0.0;
                for (int k = 0; k < K; k += 4) {
                    const float4 a = *reinterpret_cast<const float4*>(xr + k);
                    const float4 b = *reinterpret_cast<const float4*>(gr + k);
                    s0 = fma((double)a.x, (double)b.x, s0);
                    s1 = fma((double)a.y, (double)b.y, s1);
                    s2 = fma((double)a.z, (double)b.z, s2);
                    s3 = fma((double)a.w, (double)b.w, s3);
                }
                Ld[t] = (s0 + s1) + (s2 + s3);
            }
            __syncthreads();
            if (t == 0) {
                double m1 = -INFINITY, m2 = -INFINITY;
                int i1 = 0, i2 = 0;
                for (int e = 0; e < 64; ++e) {
                    const double v = Ld[e];
                    if (v > m1)      { m2 = m1; i2 = i1; m1 = v; i1 = e; }
                    else if (v > m2) { m2 = v; i2 = e; }
                }
                const double e2 = exp(m2 - m1);
                const double s  = 1.0 + e2;
                const long g = tok0 + tk;
                out[2 * g + 0] = (float)(1.0 / s);
                out[2 * g + 1] = (float)(e2 / s);
                float* oi = out + 2 * (long)M;
                oi[2 * g + 0] = (float)i1;
                oi[2 * g + 1] = (float)i2;
            }
            __syncthreads();
        }
    }
}

extern "C" void kernel_launch(void* const* d_in, const int* in_sizes, int n_in,
                              void* d_out, int out_size, void* d_ws, size_t ws_size,
                              hipStream_t stream) {
    const float* x  = (const float*)d_in[0];
    const float* gw = (const float*)d_in[1];
    float* out = (float*)d_out;

    const int K = 4096;
    const int M = in_sizes[0] / K;          // 32768 tokens
    const int nblocks = M / TPB;            // 512

    router_gemm_topk<<<nblocks, 256, 0, stream>>>(x, gw, out, M, K);
}

// Round 3
// 795.426 us; speedup vs baseline: 1.0537x; 1.0537x over previous
//
#include <hip/hip_runtime.h>
#include <math.h>

// TopK router: logits = x @ gate_w^T, softmax, top-2, renormalize.
// M=32768 tokens, K=4096, E=64 experts.
// Outputs (concat, harness reads whole buffer as float32):
//   d_out[0 .. 2M)  : top-2 weights (descending)
//   d_out[2M .. 4M) : top-2 expert indices, stored as float values
//
// R3: bf16 hi/lo split GEMM on MFMA (hh + hl + lh terms), XOR-swizzled LDS,
// fused top-2 epilogue + fp64 refine for near-tie tokens (proven in R2).

typedef __attribute__((ext_vector_type(8))) short short8;
typedef __attribute__((ext_vector_type(4))) float f32x4;

#define TPB 64      // tokens per block
#define KC  64      // K-chunk (bf16 k-values per stage)
#define TAU 1e-3f   // near-tie refine threshold (bf16x3 logit noise ~1e-5)

// byte offset inside a [64 rows][128 bytes] bf16 tile, T2-style XOR swizzle
__device__ __forceinline__ int swz(int row, int byteoff) {
    return row * 128 + (byteoff ^ ((row & 7) << 4));
}

__device__ __forceinline__ unsigned short f2bf(float f) {
    unsigned int u = __float_as_uint(f);
    u += 0x7fff + ((u >> 16) & 1);          // round-to-nearest-even
    return (unsigned short)(u >> 16);
}
__device__ __forceinline__ float bf2f(unsigned short h) {
    return __uint_as_float(((unsigned int)h) << 16);
}

__global__ __launch_bounds__(256, 2)
void router_mfma_topk(const float* __restrict__ x,
                      const float* __restrict__ gw,
                      float* __restrict__ out,
                      int M, int K) {
    // LDS: Ah @0, Al @8192, Bh @16384, Bl @24576  (each 64x64 bf16 = 8KB)
    __shared__ __align__(16) char lds[32768];
    __shared__ float Ls[64 * 68];           // logits dump, padded stride
    __shared__ int flags[TPB];
    __shared__ double Ld[64];

    const int t = threadIdx.x;
    const long tok0 = (long)blockIdx.x * TPB;

    // staging role: row 0..63 (token-local / expert), k-quarter 0..3
    const int srow = t >> 2;
    const int skq  = t & 3;
    const float* xrow = x  + (tok0 + srow) * (long)K + 16 * skq;
    const float* grow = gw + srow * (long)K + 16 * skq;

    // MFMA role
    const int lw = t >> 6;                  // wave 0..3 -> m-tile (tokens 16*lw..)
    const int ln = t & 63;
    const int frow = ln & 15;               // row/col within 16x16 tile
    const int kb   = (ln >> 4) << 4;        // 16B offset for this lane's k-group

    f32x4 acc[4];
#pragma unroll
    for (int i = 0; i < 4; ++i) acc[i] = (f32x4){0.f, 0.f, 0.f, 0.f};

    const int NC = K / KC;                  // 64 chunks

    // prologue: load chunk 0
    float4 xa[4], ga[4];
#pragma unroll
    for (int i = 0; i < 4; ++i) {
        xa[i] = *reinterpret_cast<const float4*>(xrow + 4 * i);
        ga[i] = *reinterpret_cast<const float4*>(grow + 4 * i);
    }

    for (int c = 0; c < NC; ++c) {
        // ---- convert current chunk regs -> bf16 hi/lo ----
        unsigned short hx[16], lx[16], hg[16], lg[16];
        const float* xf = reinterpret_cast<const float*>(xa);
        const float* gf = reinterpret_cast<const float*>(ga);
#pragma unroll
        for (int i = 0; i < 16; ++i) {
            float v = xf[i];
            unsigned short h = f2bf(v);
            hx[i] = h; lx[i] = f2bf(v - bf2f(h));
            float u = gf[i];
            unsigned short h2 = f2bf(u);
            hg[i] = h2; lg[i] = f2bf(u - bf2f(h2));
        }

        __syncthreads();                    // prior MFMA reads done
        // ---- ds_write: two 16B chunks per array (swizzled) ----
#pragma unroll
        for (int hh = 0; hh < 2; ++hh) {
            short8 vxh, vxl, vgh, vgl;
#pragma unroll
            for (int j = 0; j < 8; ++j) {
                vxh[j] = (short)hx[8 * hh + j];
                vxl[j] = (short)lx[8 * hh + j];
                vgh[j] = (short)hg[8 * hh + j];
                vgl[j] = (short)lg[8 * hh + j];
            }
            const int bo = swz(srow, 32 * skq + 16 * hh);
            *reinterpret_cast<short8*>(lds +     0 + bo) = vxh;
            *reinterpret_cast<short8*>(lds +  8192 + bo) = vxl;
            *reinterpret_cast<short8*>(lds + 16384 + bo) = vgh;
            *reinterpret_cast<short8*>(lds + 24576 + bo) = vgl;
        }
        __syncthreads();                    // tiles ready

        // ---- issue next chunk's global loads (in flight during MFMA) ----
        if (c + 1 < NC) {
            const int ko = (c + 1) * KC;
#pragma unroll
            for (int i = 0; i < 4; ++i) {
                xa[i] = *reinterpret_cast<const float4*>(xrow + ko + 4 * i);
                ga[i] = *reinterpret_cast<const float4*>(grow + ko + 4 * i);
            }
        }

        // ---- MFMA: hh + hl + lh over two k=32 windows ----
        const int arow = (lw << 4) + frow;
#pragma unroll
        for (int kw = 0; kw < 2; ++kw) {
            const int co = kw * 64 + kb;
            short8 ah = *reinterpret_cast<const short8*>(lds +    0 + swz(arow, co));
            short8 al = *reinterpret_cast<const short8*>(lds + 8192 + swz(arow, co));
#pragma unroll
            for (int nt = 0; nt < 4; ++nt) {
                const int brow = (nt << 4) + frow;
                short8 bh = *reinterpret_cast<const short8*>(lds + 16384 + swz(brow, co));
                short8 bl = *reinterpret_cast<const short8*>(lds + 24576 + swz(brow, co));
                acc[nt] = __builtin_amdgcn_mfma_f32_16x16x32_bf16(ah, bh, acc[nt], 0, 0, 0);
                acc[nt] = __builtin_amdgcn_mfma_f32_16x16x32_bf16(ah, bl, acc[nt], 0, 0, 0);
                acc[nt] = __builtin_amdgcn_mfma_f32_16x16x32_bf16(al, bh, acc[nt], 0, 0, 0);
            }
        }
    }

    // ---- dump logits: C/D layout col=lane&15, row=(lane>>4)*4+reg ----
#pragma unroll
    for (int nt = 0; nt < 4; ++nt) {
#pragma unroll
        for (int r = 0; r < 4; ++r) {
            const int tokl = (lw << 4) + ((ln >> 4) << 2) + r;
            const int e    = (nt << 4) + frow;
            Ls[tokl * 68 + e] = acc[nt][r];
        }
    }
    __syncthreads();

    // ---- top-3 scan + provisional output + near-tie flag ----
    if (t < TPB) {
        const float* row = Ls + (long)t * 68;
        float m1 = -INFINITY, m2 = -INFINITY, m3 = -INFINITY;
        int i1 = 0, i2 = 0;
#pragma unroll 8
        for (int e = 0; e < 64; ++e) {
            const float v = row[e];
            if (v > m1)      { m3 = m2; m2 = m1; i2 = i1; m1 = v; i1 = e; }
            else if (v > m2) { m3 = m2; m2 = v; i2 = e; }
            else if (v > m3) { m3 = v; }
        }
        const float e2 = expf(m2 - m1);
        const float s  = 1.0f + e2;

        const long g = tok0 + t;
        out[2 * g + 0] = 1.0f / s;
        out[2 * g + 1] = e2 / s;
        float* oi = out + 2 * (long)M;
        oi[2 * g + 0] = (float)i1;
        oi[2 * g + 1] = (float)i2;

        flags[t] = ((m1 - m2) < TAU) | ((m2 - m3) < TAU);
    }
    __syncthreads();

    // ---- fp64 refine for near-tie tokens (rare; block-uniform control) ----
    for (int tk = 0; tk < TPB; ++tk) {
        if (flags[tk]) {
            if (t < 64) {
                const float* xr = x + (tok0 + tk) * (long)K;
                const float* gr = gw + (long)t * (long)K;
                double s0 = 0.0, s1 = 0.0, s2 = 0.0, s3 = 0.0;
                for (int k = 0; k < K; k += 4) {
                    const float4 a = *reinterpret_cast<const float4*>(xr + k);
                    const float4 b = *reinterpret_cast<const float4*>(gr + k);
                    s0 = fma((double)a.x, (double)b.x, s0);
                    s1 = fma((double)a.y, (double)b.y, s1);
                    s2 = fma((double)a.z, (double)b.z, s2);
                    s3 = fma((double)a.w, (double)b.w, s3);
                }
                Ld[t] = (s0 + s1) + (s2 + s3);
            }
            __syncthreads();
            if (t == 0) {
                double m1 = -INFINITY, m2 = -INFINITY;
                int i1 = 0, i2 = 0;
                for (int e = 0; e < 64; ++e) {
                    const double v = Ld[e];
                    if (v > m1)      { m2 = m1; i2 = i1; m1 = v; i1 = e; }
                    else if (v > m2) { m2 = v; i2 = e; }
                }
                const double e2 = exp(m2 - m1);
                const double s  = 1.0 + e2;
                const long g = tok0 + tk;
                out[2 * g + 0] = (float)(1.0 / s);
                out[2 * g + 1] = (float)(e2 / s);
                float* oi = out + 2 * (long)M;
                oi[2 * g + 0] = (float)i1;
                oi[2 * g + 1] = (float)i2;
            }
            __syncthreads();
        }
    }
}

extern "C" void kernel_launch(void* const* d_in, const int* in_sizes, int n_in,
                              void* d_out, int out_size, void* d_ws, size_t ws_size,
                              hipStream_t stream) {
    const float* x  = (const float*)d_in[0];
    const float* gw = (const float*)d_in[1];
    float* out = (float*)d_out;

    const int K = 4096;
    const int M = in_sizes[0] / K;          // 32768 tokens
    const int nblocks = M / TPB;            // 512

    router_mfma_topk<<<nblocks, 256, 0, stream>>>(x, gw, out, M, K);
}

// Round 4
// 526.751 us; speedup vs baseline: 1.5912x; 1.5101x over previous
//
#include <hip/hip_runtime.h>
#include <hip/hip_bf16.h>
#include <math.h>

// TopK router: logits = x @ gate_w^T, softmax, top-2, renormalize.
// M=32768 tokens, K=4096, E=64 experts.
// Outputs (concat, harness reads whole buffer as float32):
//   d_out[0 .. 2M)  : top-2 weights (descending)
//   d_out[2M .. 4M) : top-2 expert indices, stored as float values
//
// R4: barrier-free main loop. Waves split K (1024 each), accumulate partial
// logits for the whole 32-token x 64-expert tile with bf16 hi/lo MFMA
// (hh+hl+lh), fragments loaded directly from global (no LDS staging).
// Single barrier + cross-wave reduce + proven top-3/TAU/fp64-refine tail.

typedef __attribute__((ext_vector_type(8))) short short8;
typedef __attribute__((ext_vector_type(4))) float f32x4;

#define TPB 32      // tokens per block
#define TAU 1e-3f   // near-tie refine threshold (bf16x3 logit noise ~1e-5)
#define LROW 68     // padded logits stride (floats)

__device__ __forceinline__ void cvt8(const float4* v, short8* hi, short8* lo) {
    const float* f = reinterpret_cast<const float*>(v);
#pragma unroll
    for (int j = 0; j < 8; ++j) {
        __hip_bfloat16 h = __float2bfloat16(f[j]);
        float r = f[j] - __bfloat162float(h);
        __hip_bfloat16 l = __float2bfloat16(r);
        (*hi)[j] = (short)*reinterpret_cast<unsigned short*>(&h);
        (*lo)[j] = (short)*reinterpret_cast<unsigned short*>(&l);
    }
}

__global__ __launch_bounds__(256, 3)
void router_mfma_topk(const float* __restrict__ x,
                      const float* __restrict__ gw,
                      float* __restrict__ out,
                      int M, int K) {
    __shared__ float Lp[4 * TPB * LROW];    // per-wave partial logits
    __shared__ int flags[TPB];
    __shared__ double Ld[64];

    const int t  = threadIdx.x;
    const int wv = t >> 6;                  // wave 0..3 -> K-slice
    const int ln = t & 63;
    const int fr = ln & 15;                 // fragment row/col
    const int q  = ln >> 4;                 // k-quarter within k=32 window
    const long tok0 = (long)blockIdx.x * TPB;

    const int kslice = K >> 2;              // 1024
    const int kbase  = wv * kslice + q * 8; // this lane's first k

    const float* pA[2];
    const float* pB[4];
#pragma unroll
    for (int mt = 0; mt < 2; ++mt)
        pA[mt] = x + (tok0 + mt * 16 + fr) * (long)K + kbase;
#pragma unroll
    for (int nt = 0; nt < 4; ++nt)
        pB[nt] = gw + (long)(nt * 16 + fr) * (long)K + kbase;

    f32x4 acc[2][4];
#pragma unroll
    for (int mt = 0; mt < 2; ++mt)
#pragma unroll
        for (int nt = 0; nt < 4; ++nt) acc[mt][nt] = (f32x4){0.f, 0.f, 0.f, 0.f};

    const int steps = kslice >> 5;          // 32 windows of k=32
    for (int s = 0; s < steps; ++s) {
        // ---- raw f32 loads: all 12 b128s issue together, one vmcnt wait ----
        float4 ra[2][2], rb[4][2];
#pragma unroll
        for (int mt = 0; mt < 2; ++mt) {
            ra[mt][0] = *reinterpret_cast<const float4*>(pA[mt]);
            ra[mt][1] = *reinterpret_cast<const float4*>(pA[mt] + 4);
        }
#pragma unroll
        for (int nt = 0; nt < 4; ++nt) {
            rb[nt][0] = *reinterpret_cast<const float4*>(pB[nt]);
            rb[nt][1] = *reinterpret_cast<const float4*>(pB[nt] + 4);
        }
        // ---- convert B fragments (hi/lo) ----
        short8 bh[4], bl[4];
#pragma unroll
        for (int nt = 0; nt < 4; ++nt) cvt8(rb[nt], &bh[nt], &bl[nt]);
        // ---- per m-tile: convert A, 3-term MFMA against 4 n-tiles ----
#pragma unroll
        for (int mt = 0; mt < 2; ++mt) {
            short8 ah, al;
            cvt8(ra[mt], &ah, &al);
#pragma unroll
            for (int nt = 0; nt < 4; ++nt) {
                acc[mt][nt] = __builtin_amdgcn_mfma_f32_16x16x32_bf16(ah, bh[nt], acc[mt][nt], 0, 0, 0);
                acc[mt][nt] = __builtin_amdgcn_mfma_f32_16x16x32_bf16(ah, bl[nt], acc[mt][nt], 0, 0, 0);
                acc[mt][nt] = __builtin_amdgcn_mfma_f32_16x16x32_bf16(al, bh[nt], acc[mt][nt], 0, 0, 0);
            }
        }
#pragma unroll
        for (int mt = 0; mt < 2; ++mt) pA[mt] += 32;
#pragma unroll
        for (int nt = 0; nt < 4; ++nt) pB[nt] += 32;
    }

    // ---- dump per-wave partials: C/D layout col=lane&15, row=(lane>>4)*4+r ----
    float* myLp = Lp + wv * (TPB * LROW);
#pragma unroll
    for (int mt = 0; mt < 2; ++mt)
#pragma unroll
        for (int nt = 0; nt < 4; ++nt)
#pragma unroll
            for (int r = 0; r < 4; ++r) {
                const int tokl = mt * 16 + q * 4 + r;
                const int e    = nt * 16 + fr;
                myLp[tokl * LROW + e] = acc[mt][nt][r];
            }
    __syncthreads();

    // ---- cross-wave reduce into Lp[0] region ----
    for (int i = t; i < TPB * LROW; i += 256)
        Lp[i] = (Lp[i] + Lp[TPB * LROW + i])
              + (Lp[2 * TPB * LROW + i] + Lp[3 * TPB * LROW + i]);
    __syncthreads();

    // ---- top-3 scan + provisional output + near-tie flag ----
    if (t < TPB) {
        const float* row = Lp + (long)t * LROW;
        float m1 = -INFINITY, m2 = -INFINITY, m3 = -INFINITY;
        int i1 = 0, i2 = 0;
#pragma unroll 8
        for (int e = 0; e < 64; ++e) {
            const float v = row[e];
            if (v > m1)      { m3 = m2; m2 = m1; i2 = i1; m1 = v; i1 = e; }
            else if (v > m2) { m3 = m2; m2 = v; i2 = e; }
            else if (v > m3) { m3 = v; }
        }
        const float e2 = expf(m2 - m1);
        const float s  = 1.0f + e2;

        const long g = tok0 + t;
        out[2 * g + 0] = 1.0f / s;
        out[2 * g + 1] = e2 / s;
        float* oi = out + 2 * (long)M;
        oi[2 * g + 0] = (float)i1;
        oi[2 * g + 1] = (float)i2;

        flags[t] = ((m1 - m2) < TAU) | ((m2 - m3) < TAU);
    }
    __syncthreads();

    // ---- fp64 refine for near-tie tokens (rare; block-uniform control) ----
    for (int tk = 0; tk < TPB; ++tk) {
        if (flags[tk]) {
            if (t < 64) {
                const float* xr = x + (tok0 + tk) * (long)K;
                const float* gr = gw + (long)t * (long)K;
                double s0 = 0.0, s1 = 0.0, s2 = 0.0, s3 = 0.0;
                for (int k = 0; k < K; k += 4) {
                    const float4 a = *reinterpret_cast<const float4*>(xr + k);
                    const float4 b = *reinterpret_cast<const float4*>(gr + k);
                    s0 = fma((double)a.x, (double)b.x, s0);
                    s1 = fma((double)a.y, (double)b.y, s1);
                    s2 = fma((double)a.z, (double)b.z, s2);
                    s3 = fma((double)a.w, (double)b.w, s3);
                }
                Ld[t] = (s0 + s1) + (s2 + s3);
            }
            __syncthreads();
            if (t == 0) {
                double m1 = -INFINITY, m2 = -INFINITY;
                int i1 = 0, i2 = 0;
                for (int e = 0; e < 64; ++e) {
                    const double v = Ld[e];
                    if (v > m1)      { m2 = m1; i2 = i1; m1 = v; i1 = e; }
                    else if (v > m2) { m2 = v; i2 = e; }
                }
                const double e2 = exp(m2 - m1);
                const double s  = 1.0 + e2;
                const long g = tok0 + tk;
                out[2 * g + 0] = (float)(1.0 / s);
                out[2 * g + 1] = (float)(e2 / s);
                float* oi = out + 2 * (long)M;
                oi[2 * g + 0] = (float)i1;
                oi[2 * g + 1] = (float)i2;
            }
            __syncthreads();
        }
    }
}

extern "C" void kernel_launch(void* const* d_in, const int* in_sizes, int n_in,
                              void* d_out, int out_size, void* d_ws, size_t ws_size,
                              hipStream_t stream) {
    const float* x  = (const float*)d_in[0];
    const float* gw = (const float*)d_in[1];
    float* out = (float*)d_out;

    const int K = 4096;
    const int M = in_sizes[0] / K;          // 32768 tokens
    const int nblocks = M / TPB;            // 1024

    router_mfma_topk<<<nblocks, 256, 0, stream>>>(x, gw, out, M, K);
}

// Round 5
// 236.858 us; speedup vs baseline: 3.5387x; 2.2239x over previous
//
#include <hip/hip_runtime.h>
#include <hip/hip_bf16.h>
#include <math.h>

// TopK router: logits = x @ gate_w^T, softmax, top-2, renormalize.
// M=32768 tokens, K=4096, E=64 experts.
// Outputs (concat, harness reads whole buffer as float32):
//   d_out[0 .. 2M)  : top-2 weights (descending)
//   d_out[2M .. 4M) : top-2 expert indices, stored as float values
//
// R5: (1) gw pre-split to packed bf16 hi/lo fragments in d_ws (no B cvt,
// contiguous 1KB wave loads), (2) explicit 2-step pipelined main loop with
// named A double-buffers + sched_barrier load pinning (R4's VGPR=60 showed
// the compiler serialized loads), (3) 4-term MFMA (hh+hl+lh+ll) -> TAU=1e-4,
// (4) parallel 256-thread fp64 refine (R4's serial refine ~85us/token).

typedef __attribute__((ext_vector_type(8))) short short8;
typedef __attribute__((ext_vector_type(4))) float f32x4;

#define TPB 32      // tokens per block
#define TAU 1e-4f   // near-tie refine threshold (4-term logit noise ~5e-6)
#define LROW 68     // padded logits stride (floats)

__device__ __forceinline__ void cvt8(const float4* v, short8* hi, short8* lo) {
    const float* f = reinterpret_cast<const float*>(v);
#pragma unroll
    for (int j = 0; j < 8; ++j) {
        __hip_bfloat16 h = __float2bfloat16(f[j]);
        float r = f[j] - __bfloat162float(h);
        __hip_bfloat16 l = __float2bfloat16(r);
        (*hi)[j] = (short)*reinterpret_cast<unsigned short*>(&h);
        (*lo)[j] = (short)*reinterpret_cast<unsigned short*>(&l);
    }
}

// Pack gw (64x4096 f32) into MFMA-fragment-ordered bf16 hi/lo arrays:
// entry ((nt*128 + w)*64 + ln) holds 8 bf16 of row nt*16+(ln&15),
// k = w*32 + (ln>>4)*8 .. +8.  A wave's 64 lanes then read 1KB contiguous.
__global__ void prep_b(const float* __restrict__ gw,
                       short8* __restrict__ bh, short8* __restrict__ bl) {
    const int tid = blockIdx.x * 256 + threadIdx.x;   // 0..32767
    const int ln  = tid & 63;
    const int w   = (tid >> 6) & 127;
    const int nt  = tid >> 13;
    const int row = nt * 16 + (ln & 15);
    const int k   = w * 32 + ((ln >> 4) << 3);
    float4 v[2];
    v[0] = *reinterpret_cast<const float4*>(gw + (long)row * 4096 + k);
    v[1] = *reinterpret_cast<const float4*>(gw + (long)row * 4096 + k + 4);
    short8 h, l;
    cvt8(v, &h, &l);
    bh[tid] = h;
    bl[tid] = l;
}

#define LOADA(BUF, S) do {                                                    \
    (BUF)[0][0] = *reinterpret_cast<const float4*>(pA0 + (S) * 32);           \
    (BUF)[0][1] = *reinterpret_cast<const float4*>(pA0 + (S) * 32 + 4);       \
    (BUF)[1][0] = *reinterpret_cast<const float4*>(pA1 + (S) * 32);           \
    (BUF)[1][1] = *reinterpret_cast<const float4*>(pA1 + (S) * 32 + 4);       \
} while (0)

#define COMPUTE(BUF, BH, BL) do {                                             \
    short8 ah0, al0, ah1, al1;                                                \
    cvt8((BUF)[0], &ah0, &al0);                                               \
    cvt8((BUF)[1], &ah1, &al1);                                               \
    _Pragma("unroll")                                                         \
    for (int nt = 0; nt < 4; ++nt) {                                          \
        acc[0][nt] = __builtin_amdgcn_mfma_f32_16x16x32_bf16(ah0, (BH)[nt], acc[0][nt], 0, 0, 0); \
        acc[0][nt] = __builtin_amdgcn_mfma_f32_16x16x32_bf16(ah0, (BL)[nt], acc[0][nt], 0, 0, 0); \
        acc[0][nt] = __builtin_amdgcn_mfma_f32_16x16x32_bf16(al0, (BH)[nt], acc[0][nt], 0, 0, 0); \
        acc[0][nt] = __builtin_amdgcn_mfma_f32_16x16x32_bf16(al0, (BL)[nt], acc[0][nt], 0, 0, 0); \
        acc[1][nt] = __builtin_amdgcn_mfma_f32_16x16x32_bf16(ah1, (BH)[nt], acc[1][nt], 0, 0, 0); \
        acc[1][nt] = __builtin_amdgcn_mfma_f32_16x16x32_bf16(ah1, (BL)[nt], acc[1][nt], 0, 0, 0); \
        acc[1][nt] = __builtin_amdgcn_mfma_f32_16x16x32_bf16(al1, (BH)[nt], acc[1][nt], 0, 0, 0); \
        acc[1][nt] = __builtin_amdgcn_mfma_f32_16x16x32_bf16(al1, (BL)[nt], acc[1][nt], 0, 0, 0); \
    }                                                                         \
} while (0)

template<bool PACKED>
__global__ __launch_bounds__(256, 4)
void router_mfma_topk(const float* __restrict__ x,
                      const float* __restrict__ gw,
                      const short8* __restrict__ bhp,
                      const short8* __restrict__ blp,
                      float* __restrict__ out,
                      int M, int K) {
    __shared__ float Lp[4 * TPB * LROW];    // per-wave partial logits
    __shared__ int flags[TPB];
    __shared__ double Ld4[4][64];

    const int t  = threadIdx.x;
    const int wv = t >> 6;                  // wave -> K-slice of 1024
    const int ln = t & 63;
    const int fr = ln & 15;
    const int q  = ln >> 4;
    const long tok0 = (long)blockIdx.x * TPB;

    const int kbase = wv * 1024 + q * 8;
    const float* pA0 = x + (tok0 + fr) * (long)K + kbase;
    const float* pA1 = x + (tok0 + 16 + fr) * (long)K + kbase;
    const float* pBf[4];
#pragma unroll
    for (int nt = 0; nt < 4; ++nt)
        pBf[nt] = gw + (long)(nt * 16 + fr) * (long)K + kbase;
    const int bidx0 = (wv * 32) * 64 + ln;  // + nt*8192 + s*64

    f32x4 acc[2][4];
#pragma unroll
    for (int mt = 0; mt < 2; ++mt)
#pragma unroll
        for (int nt = 0; nt < 4; ++nt) acc[mt][nt] = (f32x4){0.f, 0.f, 0.f, 0.f};

    float4 A0[2][2], A1[2][2];
    LOADA(A0, 0);

    for (int it = 0; it < 16; ++it) {
        const int s0 = 2 * it;
        // ---- half-step 0: issue B(s0) then A(s0+1); compute A0 ----
        short8 bh0[4], bl0[4];
        if constexpr (PACKED) {
#pragma unroll
            for (int nt = 0; nt < 4; ++nt) {
                const int idx = bidx0 + nt * 8192 + s0 * 64;
                bh0[nt] = bhp[idx];
                bl0[nt] = blp[idx];
            }
        } else {
#pragma unroll
            for (int nt = 0; nt < 4; ++nt) {
                float4 v[2];
                v[0] = *reinterpret_cast<const float4*>(pBf[nt] + s0 * 32);
                v[1] = *reinterpret_cast<const float4*>(pBf[nt] + s0 * 32 + 4);
                cvt8(v, &bh0[nt], &bl0[nt]);
            }
        }
        LOADA(A1, s0 + 1);
        __builtin_amdgcn_sched_barrier(0);
        COMPUTE(A0, bh0, bl0);

        // ---- half-step 1: issue B(s0+1) then A(s0+2); compute A1 ----
        short8 bh1[4], bl1[4];
        if constexpr (PACKED) {
#pragma unroll
            for (int nt = 0; nt < 4; ++nt) {
                const int idx = bidx0 + nt * 8192 + (s0 + 1) * 64;
                bh1[nt] = bhp[idx];
                bl1[nt] = blp[idx];
            }
        } else {
#pragma unroll
            for (int nt = 0; nt < 4; ++nt) {
                float4 v[2];
                v[0] = *reinterpret_cast<const float4*>(pBf[nt] + (s0 + 1) * 32);
                v[1] = *reinterpret_cast<const float4*>(pBf[nt] + (s0 + 1) * 32 + 4);
                cvt8(v, &bh1[nt], &bl1[nt]);
            }
        }
        if (it < 15) LOADA(A0, s0 + 2);
        __builtin_amdgcn_sched_barrier(0);
        COMPUTE(A1, bh1, bl1);
    }

    // ---- dump per-wave partials: C/D layout col=lane&15, row=q*4+r ----
    float* myLp = Lp + wv * (TPB * LROW);
#pragma unroll
    for (int mt = 0; mt < 2; ++mt)
#pragma unroll
        for (int nt = 0; nt < 4; ++nt)
#pragma unroll
            for (int r = 0; r < 4; ++r) {
                const int tokl = mt * 16 + q * 4 + r;
                const int e    = nt * 16 + fr;
                myLp[tokl * LROW + e] = acc[mt][nt][r];
            }
    __syncthreads();

    // ---- cross-wave reduce into Lp[0] region ----
    for (int i = t; i < TPB * LROW; i += 256)
        Lp[i] = (Lp[i] + Lp[TPB * LROW + i])
              + (Lp[2 * TPB * LROW + i] + Lp[3 * TPB * LROW + i]);
    __syncthreads();

    // ---- top-3 scan + provisional output + near-tie flag ----
    if (t < TPB) {
        const float* row = Lp + (long)t * LROW;
        float m1 = -INFINITY, m2 = -INFINITY, m3 = -INFINITY;
        int i1 = 0, i2 = 0;
#pragma unroll 8
        for (int e = 0; e < 64; ++e) {
            const float v = row[e];
            if (v > m1)      { m3 = m2; m2 = m1; i2 = i1; m1 = v; i1 = e; }
            else if (v > m2) { m3 = m2; m2 = v; i2 = e; }
            else if (v > m3) { m3 = v; }
        }
        const float e2 = expf(m2 - m1);
        const float s  = 1.0f + e2;

        const long g = tok0 + t;
        out[2 * g + 0] = 1.0f / s;
        out[2 * g + 1] = e2 / s;
        float* oi = out + 2 * (long)M;
        oi[2 * g + 0] = (float)i1;
        oi[2 * g + 1] = (float)i2;

        flags[t] = ((m1 - m2) < TAU) | ((m2 - m3) < TAU);
    }
    __syncthreads();

    // ---- fp64 refine, all 256 threads cooperate (wave=K-chunk, lane=expert) ----
    for (int tk = 0; tk < TPB; ++tk) {
        if (flags[tk]) {
            const float* xr = x + (tok0 + tk) * (long)K + wv * 1024;
            const float* gr = gw + (long)ln * (long)K + wv * 1024;
            double s0 = 0.0, s1 = 0.0, s2 = 0.0, s3 = 0.0;
            for (int k = 0; k < 1024; k += 4) {
                const float4 a = *reinterpret_cast<const float4*>(xr + k);
                const float4 b = *reinterpret_cast<const float4*>(gr + k);
                s0 = fma((double)a.x, (double)b.x, s0);
                s1 = fma((double)a.y, (double)b.y, s1);
                s2 = fma((double)a.z, (double)b.z, s2);
                s3 = fma((double)a.w, (double)b.w, s3);
            }
            Ld4[wv][ln] = (s0 + s1) + (s2 + s3);
            __syncthreads();
            if (t == 0) {
                double m1 = -INFINITY, m2 = -INFINITY;
                int i1 = 0, i2 = 0;
                for (int e = 0; e < 64; ++e) {
                    const double v = Ld4[0][e] + Ld4[1][e] + Ld4[2][e] + Ld4[3][e];
                    if (v > m1)      { m2 = m1; i2 = i1; m1 = v; i1 = e; }
                    else if (v > m2) { m2 = v; i2 = e; }
                }
                const double e2 = exp(m2 - m1);
                const double s  = 1.0 + e2;
                const long g = tok0 + tk;
                out[2 * g + 0] = (float)(1.0 / s);
                out[2 * g + 1] = (float)(e2 / s);
                float* oi = out + 2 * (long)M;
                oi[2 * g + 0] = (float)i1;
                oi[2 * g + 1] = (float)i2;
            }
            __syncthreads();
        }
    }
}

extern "C" void kernel_launch(void* const* d_in, const int* in_sizes, int n_in,
                              void* d_out, int out_size, void* d_ws, size_t ws_size,
                              hipStream_t stream) {
    const float* x  = (const float*)d_in[0];
    const float* gw = (const float*)d_in[1];
    float* out = (float*)d_out;

    const int K = 4096;
    const int M = in_sizes[0] / K;          // 32768 tokens
    const int nblocks = M / TPB;            // 1024

    if (ws_size >= (1u << 20)) {
        short8* bh = (short8*)d_ws;
        short8* bl = bh + 32768;
        prep_b<<<128, 256, 0, stream>>>(gw, bh, bl);
        router_mfma_topk<true><<<nblocks, 256, 0, stream>>>(x, gw, bh, bl, out, M, K);
    } else {
        router_mfma_topk<false><<<nblocks, 256, 0, stream>>>(x, gw, nullptr, nullptr, out, M, K);
    }
}